// Round 3
// baseline (224.920 us; speedup 1.0000x reference)
//
#include <hip/hip_runtime.h>
#include <hip/hip_fp16.h>

// ChebyshevKAN: y[b,o] = sum_{i,j} U_j(tanh(x[b,i])) * C[i,o,j]
//   B=65536, I=512, O=32, degree 8 (j=0..8).
// Round 3 (= round 2 + cvt_pkrtz type fix): barrier-free. f16 MFMA GEMM
// [B x 4096] * [4096 x 32], A generated in registers from the Chebyshev
// recurrence (fp32), B pre-swizzled to exact fragment order and read DIRECTLY
// from global (L1/L2-resident, 16 KB/chunk) -- no LDS, no __syncthreads,
// 1 wave per block, grid 2048 (8 blocks/CU).
//   - j=0 term (U_0=1) folded into bias[o] = sum_i C[i,o,0].
//   - chunk ci = 32 i's; K-32 MFMA step = one j in 1..8.
//   - A-frag 16x16x32: A[m=lane&15][k=quad*8+e] -> lane owns 8 consecutive i.
//   - x for chunk ci+1 prefetched into registers during chunk ci's compute.

typedef _Float16 half8 __attribute__((ext_vector_type(8)));
typedef __fp16  fp16x2 __attribute__((ext_vector_type(2)));   // cvt_pkrtz return type
typedef float float4v __attribute__((ext_vector_type(4)));

#define N_I 512
#define N_O 32
#define N_CHUNKS 16
#define STEPS 8
#define CHUNK_F16 8192   // 8 steps * 2 tiles * 64 lanes * 8 f16

// ---- prep: pack B to fragment order (blocks 0..511) + bias (block 512) ----
// B_sw flat index: ((s_glob*2 + t)*64 + L)*8 + jj
//   s_glob = ci*8 + (j-1); k_local(ii) = (L>>4)*8 + jj; i = ci*32 + ii
//   o = t*16 + (L&15)     [layout verified: round 1 passed, absmax 0.0625]
__global__ void prep(const float* __restrict__ coeffs, _Float16* __restrict__ bsw,
                     float* __restrict__ bias) {
    if (blockIdx.x == 512) {
        int o = threadIdx.x >> 3, p = threadIdx.x & 7;   // 8 threads per o, same wave
        float s = 0.f;
        for (int i = p; i < N_I; i += 8) s += coeffs[(i * 32 + o) * 9];
        for (int off = 4; off; off >>= 1) s += __shfl_down(s, off, 8);
        if (p == 0) bias[o] = s;
        return;
    }
    int id = blockIdx.x * 256 + threadIdx.x;
    int jj = id & 7;
    int L  = (id >> 3) & 63;
    int t  = (id >> 9) & 1;
    int s  = id >> 10;                 // 0..127
    int ci = s >> 3, sl = s & 7;
    int j  = sl + 1;                   // 1..8
    int ii = ((L >> 4) << 3) + jj;
    int i  = ci * 32 + ii;
    int o  = t * 16 + (L & 15);
    bsw[id] = (_Float16)coeffs[(i * 32 + o) * 9 + j];
}

__device__ __forceinline__ float fast_tanh(float v) {
    // tanh(v) = 1 - 2/(exp(2v)+1); graceful at +-inf. Error far below f16 quant.
    float e = __expf(2.0f * v);
    return __builtin_fmaf(-2.0f, __builtin_amdgcn_rcpf(e + 1.0f), 1.0f);
}

__device__ __forceinline__ half8 pack8(const float* u) {
    union { fp16x2 h[4]; half8 v; } r;
    r.h[0] = __builtin_amdgcn_cvt_pkrtz(u[0], u[1]);
    r.h[1] = __builtin_amdgcn_cvt_pkrtz(u[2], u[3]);
    r.h[2] = __builtin_amdgcn_cvt_pkrtz(u[4], u[5]);
    r.h[3] = __builtin_amdgcn_cvt_pkrtz(u[6], u[7]);
    return r.v;
}

// ---- main: 1 wave per block, 32 rows (2 M-tiles) x 32 cols (2 N-tiles) ----
__global__ __launch_bounds__(64) void cheby_main(
        const float* __restrict__ x, const _Float16* __restrict__ bsw,
        const float* __restrict__ bias, float* __restrict__ y) {
    const int L  = threadIdx.x;
    const int q  = L >> 4;        // quad 0..3
    const int mr = L & 15;        // row-in-tile / col-in-tile
    const int m0 = blockIdx.x * 32;
    const float* xr0 = x + (size_t)(m0 + mr) * N_I + q * 8;   // M-tile 0 row
    const float* xr1 = xr0 + 16 * N_I;                        // M-tile 1 row

    // chunk 0 x
    float4v xa = *(const float4v*)(xr0);
    float4v xb = *(const float4v*)(xr0 + 4);
    float4v xc = *(const float4v*)(xr1);
    float4v xd = *(const float4v*)(xr1 + 4);

    float4v acc[2][2];
#pragma unroll
    for (int a = 0; a < 2; ++a)
#pragma unroll
        for (int b = 0; b < 2; ++b)
#pragma unroll
            for (int e = 0; e < 4; ++e) acc[a][b][e] = 0.f;

    const _Float16* bc = bsw + L * 8;

    for (int ci = 0; ci < N_CHUNKS; ++ci) {
        // all 16 B-fragment loads for this chunk (L1/L2-hot, issued up-front)
        half8 bf[STEPS][2];
#pragma unroll
        for (int s = 0; s < STEPS; ++s) {
            bf[s][0] = *(const half8*)(bc + ci * CHUNK_F16 + (s * 2 + 0) * 512);
            bf[s][1] = *(const half8*)(bc + ci * CHUNK_F16 + (s * 2 + 1) * 512);
        }

        // tanh + recurrence init from x already in registers
        float w0[8], w1[8], up0[8], uc0[8], up1[8], uc1[8];
#pragma unroll
        for (int e = 0; e < 4; ++e) {
            w0[e]     = 2.0f * fast_tanh(xa[e]);
            w0[e + 4] = 2.0f * fast_tanh(xb[e]);
            w1[e]     = 2.0f * fast_tanh(xc[e]);
            w1[e + 4] = 2.0f * fast_tanh(xd[e]);
        }
#pragma unroll
        for (int e = 0; e < 8; ++e) {    // U_0 = 1, U_1 = 2*xt
            up0[e] = 1.0f; uc0[e] = w0[e];
            up1[e] = 1.0f; uc1[e] = w1[e];
        }

        // prefetch next chunk's x (use -> consume gap = one full chunk)
        if (ci < N_CHUNKS - 1) {
            const int o = (ci + 1) * 32;
            xa = *(const float4v*)(xr0 + o);
            xb = *(const float4v*)(xr0 + o + 4);
            xc = *(const float4v*)(xr1 + o);
            xd = *(const float4v*)(xr1 + o + 4);
        }

#pragma unroll
        for (int s = 0; s < STEPS; ++s) {    // j = s+1
            const half8 a0 = pack8(uc0);
            const half8 a1 = pack8(uc1);
            acc[0][0] = __builtin_amdgcn_mfma_f32_16x16x32_f16(a0, bf[s][0], acc[0][0], 0, 0, 0);
            acc[0][1] = __builtin_amdgcn_mfma_f32_16x16x32_f16(a0, bf[s][1], acc[0][1], 0, 0, 0);
            acc[1][0] = __builtin_amdgcn_mfma_f32_16x16x32_f16(a1, bf[s][0], acc[1][0], 0, 0, 0);
            acc[1][1] = __builtin_amdgcn_mfma_f32_16x16x32_f16(a1, bf[s][1], acc[1][1], 0, 0, 0);
            // U_{n+1} = w*U_n - U_{n-1}
#pragma unroll
            for (int e = 0; e < 8; ++e) {
                float n0 = __builtin_fmaf(w0[e], uc0[e], -up0[e]);
                float n1 = __builtin_fmaf(w1[e], uc1[e], -up1[e]);
                up0[e] = uc0[e]; uc0[e] = n0;
                up1[e] = uc1[e]; uc1[e] = n1;
            }
        }
    }

    // epilogue: C/D layout row = q*4 + e, col = mr (verified round 1)
    const float b_n0 = bias[mr];
    const float b_n1 = bias[16 + mr];
#pragma unroll
    for (int mt = 0; mt < 2; ++mt) {
#pragma unroll
        for (int e = 0; e < 4; ++e) {
            const int r = m0 + mt * 16 + q * 4 + e;
            y[(size_t)r * N_O + mr]      = acc[mt][0][e] + b_n0;
            y[(size_t)r * N_O + 16 + mr] = acc[mt][1][e] + b_n1;
        }
    }
}

extern "C" void kernel_launch(void* const* d_in, const int* in_sizes, int n_in,
                              void* d_out, int out_size, void* d_ws, size_t ws_size,
                              hipStream_t stream) {
    const float* x      = (const float*)d_in[0];
    const float* coeffs = (const float*)d_in[1];
    float* yout = (float*)d_out;

    _Float16* bsw = (_Float16*)d_ws;                               // 131072 f16 = 256KB
    float* bias   = (float*)((char*)d_ws + 131072 * sizeof(_Float16));

    prep<<<513, 256, 0, stream>>>(coeffs, bsw, bias);
    cheby_main<<<2048, 64, 0, stream>>>(x, bsw, bias, yout);
}

// Round 4
// 215.513 us; speedup vs baseline: 1.0436x; 1.0436x over previous
//
#include <hip/hip_runtime.h>
#include <hip/hip_fp16.h>

// ChebyshevKAN: y[b,o] = sum_{i,j} U_j(tanh(x[b,i])) * C[i,o,j]
//   B=65536, I=512, O=32, degree 8 (j=0..8).
// Round 4: LDS-shared B (round-1 structure) with the barrier stall fixed:
//   - barrier PERIOD = 2 chunks (64 i's): inter-barrier compute ~1800 cy
//     > HBM latency (~900 cy), so the vmcnt(0) drain at __syncthreads no
//     longer exposes x-prefetch latency.
//   - B staged via __builtin_amdgcn_global_load_lds (width 16), double
//     buffered: 2 x 32 KB LDS, 2 blocks/CU (128 KB <= 160 KB).
//   - x for the NEXT period register-prefetched right after the barrier.
//   - j=0 folded into bias; A generated in registers (fp32 recurrence,
//     pkrtz to f16 at MFMA input) -- verified absmax 0.0625.
// Block 256 = 4 waves; wave = 32 rows (2 M-tiles) x 32 cols (2 N-tiles);
// grid 512 (2 blocks/CU, 8 waves/CU).

typedef _Float16 half8 __attribute__((ext_vector_type(8)));
typedef __fp16  fp16x2 __attribute__((ext_vector_type(2)));   // cvt_pkrtz return type
typedef float float4v __attribute__((ext_vector_type(4)));

#define N_I 512
#define N_O 32
#define N_PERIODS 8
#define STEPS 8
#define CHUNK_F16 8192        // one 32-i chunk of packed B, in f16 elements
#define PERIOD_F16 16384      // two chunks
#define PERIOD_BYTES 32768

// ---- prep: pack B to fragment order (blocks 0..511) + bias (block 512) ----
// B_sw flat index: ((s_glob*2 + t)*64 + L)*8 + jj
//   s_glob = ci*8 + (j-1); k_local(ii) = (L>>4)*8 + jj; i = ci*32 + ii
//   o = t*16 + (L&15)     [layout verified: rounds 1 & 3 passed]
__global__ void prep(const float* __restrict__ coeffs, _Float16* __restrict__ bsw,
                     float* __restrict__ bias) {
    if (blockIdx.x == 512) {
        int o = threadIdx.x >> 3, p = threadIdx.x & 7;
        float s = 0.f;
        for (int i = p; i < N_I; i += 8) s += coeffs[(i * 32 + o) * 9];
        for (int off = 4; off; off >>= 1) s += __shfl_down(s, off, 8);
        if (p == 0) bias[o] = s;
        return;
    }
    int id = blockIdx.x * 256 + threadIdx.x;
    int jj = id & 7;
    int L  = (id >> 3) & 63;
    int t  = (id >> 9) & 1;
    int s  = id >> 10;
    int ci = s >> 3, sl = s & 7;
    int j  = sl + 1;
    int ii = ((L >> 4) << 3) + jj;
    int i  = ci * 32 + ii;
    int o  = t * 16 + (L & 15);
    bsw[id] = (_Float16)coeffs[(i * 32 + o) * 9 + j];
}

__device__ __forceinline__ float fast_tanh(float v) {
    float e = __expf(2.0f * v);
    return __builtin_fmaf(-2.0f, __builtin_amdgcn_rcpf(e + 1.0f), 1.0f);
}

__device__ __forceinline__ half8 pack8(const float* u) {
    union { fp16x2 h[4]; half8 v; } r;
    r.h[0] = __builtin_amdgcn_cvt_pkrtz(u[0], u[1]);
    r.h[1] = __builtin_amdgcn_cvt_pkrtz(u[2], u[3]);
    r.h[2] = __builtin_amdgcn_cvt_pkrtz(u[4], u[5]);
    r.h[3] = __builtin_amdgcn_cvt_pkrtz(u[6], u[7]);
    return r.v;
}

__global__ __launch_bounds__(256, 2) void cheby_main(
        const float* __restrict__ x, const _Float16* __restrict__ bsw,
        const float* __restrict__ bias, float* __restrict__ y) {
    __shared__ __align__(16) _Float16 bl[2][PERIOD_F16];   // 2 x 32 KB double buffer

    const int tid = threadIdx.x;
    const int wv  = tid >> 6;
    const int L   = tid & 63;
    const int q   = L >> 4;
    const int mr  = L & 15;
    const int m0  = blockIdx.x * 128 + wv * 32;
    const float* xr0 = x + (size_t)(m0 + mr) * N_I + q * 8;   // M-tile 0 row
    const float* xr1 = xr0 + 16 * N_I;                        // M-tile 1 row
    const char* gB = (const char*)bsw;

    float4v acc[2][2];
#pragma unroll
    for (int a = 0; a < 2; ++a)
#pragma unroll
        for (int b = 0; b < 2; ++b)
#pragma unroll
            for (int e = 0; e < 4; ++e) acc[a][b][e] = 0.f;

    // stage one 32KB period into bl[buf] via global_load_lds (wave-uniform
    // LDS base + lane*16; pack order is exactly linear -> compatible)
    auto stage = [&](int p, int buf) {
        const char* gsrc = gB + (size_t)p * PERIOD_BYTES + wv * 8192 + L * 16;
        char* lds = (char*)&bl[buf][0] + wv * 8192;
#pragma unroll
        for (int it = 0; it < 8; ++it) {
            __builtin_amdgcn_global_load_lds(
                (const __attribute__((address_space(1))) void*)(gsrc + it * 1024),
                (__attribute__((address_space(3))) void*)(lds + it * 1024),
                16, 0, 0);
        }
    };

    auto loadx = [&](int p, float4v* v) {
#pragma unroll
        for (int c = 0; c < 2; ++c) {
            const int o = (p * 2 + c) * 32;
            v[c * 4 + 0] = *(const float4v*)(xr0 + o);
            v[c * 4 + 1] = *(const float4v*)(xr0 + o + 4);
            v[c * 4 + 2] = *(const float4v*)(xr1 + o);
            v[c * 4 + 3] = *(const float4v*)(xr1 + o + 4);
        }
    };

    // one 32-i chunk: tanh + fp32 Chebyshev recurrence in regs, 8 K-steps
    auto chunk = [&](const _Float16* bb, float4v xa, float4v xb,
                     float4v xc, float4v xd) {
        float w0[8], w1[8], up0[8], uc0[8], up1[8], uc1[8];
#pragma unroll
        for (int e = 0; e < 4; ++e) {
            w0[e]     = 2.0f * fast_tanh(xa[e]);
            w0[e + 4] = 2.0f * fast_tanh(xb[e]);
            w1[e]     = 2.0f * fast_tanh(xc[e]);
            w1[e + 4] = 2.0f * fast_tanh(xd[e]);
        }
#pragma unroll
        for (int e = 0; e < 8; ++e) {          // U_0 = 1, U_1 = 2*xt
            up0[e] = 1.0f; uc0[e] = w0[e];
            up1[e] = 1.0f; uc1[e] = w1[e];
        }
#pragma unroll
        for (int s = 0; s < STEPS; ++s) {      // j = s+1
            const half8 a0 = pack8(uc0);
            const half8 a1 = pack8(uc1);
            const half8 b0 = *(const half8*)(bb + (s * 2 + 0) * 512 + L * 8);
            const half8 b1 = *(const half8*)(bb + (s * 2 + 1) * 512 + L * 8);
            acc[0][0] = __builtin_amdgcn_mfma_f32_16x16x32_f16(a0, b0, acc[0][0], 0, 0, 0);
            acc[0][1] = __builtin_amdgcn_mfma_f32_16x16x32_f16(a0, b1, acc[0][1], 0, 0, 0);
            acc[1][0] = __builtin_amdgcn_mfma_f32_16x16x32_f16(a1, b0, acc[1][0], 0, 0, 0);
            acc[1][1] = __builtin_amdgcn_mfma_f32_16x16x32_f16(a1, b1, acc[1][1], 0, 0, 0);
#pragma unroll
            for (int e = 0; e < 8; ++e) {      // U_{n+1} = w*U_n - U_{n-1}
                float n0 = __builtin_fmaf(w0[e], uc0[e], -up0[e]);
                float n1 = __builtin_fmaf(w1[e], uc1[e], -up1[e]);
                up0[e] = uc0[e]; uc0[e] = n0;
                up1[e] = uc1[e]; uc1[e] = n1;
            }
        }
    };

    float4v cur[8], nxt[8];
    stage(0, 0);
    loadx(0, cur);
    __syncthreads();                            // startup drain (once)

    for (int p = 0; p < N_PERIODS; ++p) {
        const int buf = p & 1;
        if (p < N_PERIODS - 1) {
            stage(p + 1, buf ^ 1);              // vmem -> LDS, drained at next barrier
            loadx(p + 1, nxt);                  // ~1800 cy ahead of use
        }
        chunk(&bl[buf][0],    cur[0], cur[1], cur[2], cur[3]);
        chunk(&bl[buf][8192], cur[4], cur[5], cur[6], cur[7]);
#pragma unroll
        for (int k = 0; k < 8; ++k) cur[k] = nxt[k];
        __syncthreads();                        // staging+x long complete by now
    }

    // epilogue: C/D layout row = q*4 + e, col = mr (verified rounds 1 & 3)
    const float b_n0 = bias[mr];
    const float b_n1 = bias[16 + mr];
#pragma unroll
    for (int mt = 0; mt < 2; ++mt) {
#pragma unroll
        for (int e = 0; e < 4; ++e) {
            const int r = m0 + mt * 16 + q * 4 + e;
            y[(size_t)r * N_O + mr]      = acc[mt][0][e] + b_n0;
            y[(size_t)r * N_O + 16 + mr] = acc[mt][1][e] + b_n1;
        }
    }
}

extern "C" void kernel_launch(void* const* d_in, const int* in_sizes, int n_in,
                              void* d_out, int out_size, void* d_ws, size_t ws_size,
                              hipStream_t stream) {
    const float* x      = (const float*)d_in[0];
    const float* coeffs = (const float*)d_in[1];
    float* yout = (float*)d_out;

    _Float16* bsw = (_Float16*)d_ws;                               // 131072 f16 = 256KB
    float* bias   = (float*)((char*)d_ws + 131072 * sizeof(_Float16));

    prep<<<513, 256, 0, stream>>>(coeffs, bsw, bias);
    cheby_main<<<512, 256, 0, stream>>>(x, bsw, bias, yout);
}